// Round 1
// baseline (116.216 us; speedup 1.0000x reference)
//
#include <hip/hip_runtime.h>

typedef unsigned short u16;
typedef unsigned int   u32;

using bf16x8 = __attribute__((ext_vector_type(8))) short;
using f32x4  = __attribute__((ext_vector_type(4))) float;

#define NB   64      // batch
#define NE   8       // experts
#define DIN  320
#define NP   196     // real patches per image
#define MPAD 256     // padded rows per image
#define CK   768     // inner dim (C*P*P)
#define CN   768     // out features

#define BM 64
#define BN 128
#define BK 32

__device__ __forceinline__ u16 f2bf(float f) {
    u32 u = __builtin_bit_cast(u32, f);
    u += 0x7fffu + ((u >> 16) & 1u);
    return (u16)(u >> 16);
}

// row-local chunk swizzle: permute the four 16B chunks of each 64B row.
// byte ^= ((byte>>7)&3)<<4  -> c' = c ^ ((row>>1)&3); involution (row bits live
// at >=bit6 and only bits 4..5 are toggled); spreads a 16-lane ds_read_b128
// group over 8 distinct 16B bank slots (2-way = free per m136).
__device__ __forceinline__ u32 swz(u32 byte) {
    return byte ^ (((byte >> 7) & 3u) << 4);
}

// ---------------- gating + loss ----------------
__global__ void gate_kernel(const float* __restrict__ g,
                            const float* __restrict__ noise,
                            const float* __restrict__ w_gate,
                            const float* __restrict__ w_noise,
                            int* __restrict__ eid,
                            float* __restrict__ loss_out)
{
    __shared__ float sProb[NB][NE];
    __shared__ int   sTop[NB];
    __shared__ float sImp[NE];
    __shared__ float sLoad[NE];
    int b = threadIdx.x;  // blockDim.x == 64
    {
        float cl[NE], nz[NE];
        #pragma unroll
        for (int e = 0; e < NE; ++e) { cl[e] = 0.f; nz[e] = 0.f; }
        const float* gr = g + b * DIN;
        for (int i = 0; i < DIN; ++i) {
            float gv = gr[i];
            #pragma unroll
            for (int e = 0; e < NE; ++e) {
                cl[e] = fmaf(gv, w_gate[i * NE + e], cl[e]);
                nz[e] = fmaf(gv, w_noise[i * NE + e], nz[e]);
            }
        }
        float sd[NE], ny[NE];
        #pragma unroll
        for (int e = 0; e < NE; ++e) {
            float xx = nz[e];
            // jax.nn.softplus == logaddexp(x,0) == max(x,0)+log1p(exp(-|x|))
            float sp = fmaxf(xx, 0.f) + log1pf(expf(-fabsf(xx)));
            sd[e] = sp + 0.01f;
            ny[e] = fmaf(noise[b * NE + e], sd[e], cl[e]);
        }
        float v1 = -1e30f, v2 = -1e30f; int i1 = 0;
        #pragma unroll
        for (int e = 0; e < NE; ++e) {
            float v = ny[e];
            if (v > v1) { v2 = v1; v1 = v; i1 = e; }
            else if (v > v2) { v2 = v; }
        }
        sTop[b] = i1;
        eid[b]  = i1;
        #pragma unroll
        for (int e = 0; e < NE; ++e) {
            // is_in: noisy > (k+1)-th value (v2); else compare vs k-th (v1)
            float thr = (ny[e] > v2) ? v2 : v1;
            float z = (cl[e] - thr) / sd[e];
            sProb[b][e] = 0.5f * (1.0f + erff(z * 0.7071067811865476f));
        }
    }
    __syncthreads();
    if (b < NE) {  // deterministic serial reduction per expert
        float imp = 0.f, ld = 0.f;
        for (int i = 0; i < NB; ++i) {
            imp += (sTop[i] == b) ? 1.0f : 0.0f;
            ld  += sProb[i][b];
        }
        sImp[b] = imp; sLoad[b] = ld;
    }
    __syncthreads();
    if (b == 0) {
        float mi = 0.f, ml = 0.f;
        for (int e = 0; e < NE; ++e) { mi += sImp[e]; ml += sLoad[e]; }
        mi *= (1.0f / NE); ml *= (1.0f / NE);
        float vi = 0.f, vl = 0.f;
        for (int e = 0; e < NE; ++e) {
            float d1 = sImp[e] - mi;  vi += d1 * d1;
            float d2 = sLoad[e] - ml; vl += d2 * d2;
        }
        vi *= (1.0f / (NE - 1)); vl *= (1.0f / (NE - 1));  // ddof=1
        loss_out[0] = (vi / (mi * mi + 1e-10f) + vl / (ml * ml + 1e-10f)) * 0.01f;
    }
}

// ---------------- w_exp fp32 -> bf16 (layout already [E][768][768]) ----------------
__global__ void wconv_kernel(const float* __restrict__ w, u16* __restrict__ wb)
{
    int idx = blockIdx.x * 256 + threadIdx.x;     // 8 elems per thread
    const float* src = w + (size_t)idx * 8;
    float4 f0 = *reinterpret_cast<const float4*>(src);
    float4 f1 = *reinterpret_cast<const float4*>(src + 4);
    uint4 o;
    o.x = (u32)f2bf(f0.x) | ((u32)f2bf(f0.y) << 16);
    o.y = (u32)f2bf(f0.z) | ((u32)f2bf(f0.w) << 16);
    o.z = (u32)f2bf(f1.x) | ((u32)f2bf(f1.y) << 16);
    o.w = (u32)f2bf(f1.z) | ((u32)f2bf(f1.w) << 16);
    *reinterpret_cast<uint4*>(wb + (size_t)idx * 8) = o;
}

// ---------------- patchify + bf16, pad rows [196,256) with zeros ----------------
__global__ void patchify_kernel(const float* __restrict__ x, u16* __restrict__ patches)
{
    int idx = blockIdx.x * 256 + threadIdx.x;     // total 64*256*96
    int i8 = idx % 96;
    int p  = (idx / 96) % MPAD;
    int b  = idx / (96 * MPAD);
    u16* dst = patches + ((size_t)(b * MPAD + p)) * CK + i8 * 8;
    if (p >= NP) {
        uint4 z; z.x = 0; z.y = 0; z.z = 0; z.w = 0;
        *reinterpret_cast<uint4*>(dst) = z;
        return;
    }
    int gh = p / 14, gw = p % 14;
    int i0 = i8 * 8;
    int c   = i0 >> 8;        // /256
    int rem = i0 & 255;
    int ph  = rem >> 4;
    int pw0 = rem & 15;       // 0 or 8
    const float* src = x + (((size_t)(b * 3 + c) * 224 + gh * 16 + ph) * 224 + gw * 16 + pw0);
    float4 f0 = *reinterpret_cast<const float4*>(src);
    float4 f1 = *reinterpret_cast<const float4*>(src + 4);
    uint4 o;
    o.x = (u32)f2bf(f0.x) | ((u32)f2bf(f0.y) << 16);
    o.y = (u32)f2bf(f0.z) | ((u32)f2bf(f0.w) << 16);
    o.z = (u32)f2bf(f1.x) | ((u32)f2bf(f1.y) << 16);
    o.w = (u32)f2bf(f1.z) | ((u32)f2bf(f1.w) << 16);
    *reinterpret_cast<uint4*>(dst) = o;
}

// ---------------- expert-selected batched GEMM ----------------
// grid: (N/BN=6, MPAD/BM=4, NB=64), 256 threads = 4 waves, wave tile 32x64
__global__ __launch_bounds__(256) void gemm_kernel(
    const u16* __restrict__ patches,
    const u16* __restrict__ wb,
    const float* __restrict__ b_exp,
    const int* __restrict__ eid,
    float* __restrict__ out)
{
    __shared__ char smem[(BM + BN) * BK * 2];   // A 4KB + B 8KB
    char* sA = smem;
    char* sB = smem + BM * BK * 2;

    const int t  = threadIdx.x;
    const int b  = blockIdx.z;
    const int m0 = blockIdx.y * BM;
    const int n0 = blockIdx.x * BN;
    const int e  = eid[b];

    const int l  = t & 63;
    const int w  = t >> 6;
    const int wm = w & 1;
    const int wn = w >> 1;

    // staging source addresses
    const int rowA = t >> 2, cA = t & 3;
    const u16* aSrc = patches + ((size_t)(b * MPAD) + m0 + rowA) * CK + cA * 8;
    const u32 swA = swz((u32)(rowA * 64 + cA * 16));

    const int rowB = t >> 1, hB = t & 1;
    const u16* bSrc = wb + (size_t)e * CK * CN + (size_t)(n0 + rowB) * CK + hB * 16;
    const u32 swB0 = swz((u32)(rowB * 64 + (2 * hB) * 16));
    const u32 swB1 = swz((u32)(rowB * 64 + (2 * hB + 1) * 16));

    // fragment read offsets (same swizzle)
    u32 raOff[2], rbOff[4];
    #pragma unroll
    for (int fm = 0; fm < 2; ++fm) {
        int row = wm * 32 + fm * 16 + (l & 15);
        raOff[fm] = swz((u32)(row * 64 + (l >> 4) * 16));
    }
    #pragma unroll
    for (int fn = 0; fn < 4; ++fn) {
        int row = wn * 64 + fn * 16 + (l & 15);
        rbOff[fn] = swz((u32)(row * 64 + (l >> 4) * 16));
    }

    f32x4 acc[2][4];
    #pragma unroll
    for (int fm = 0; fm < 2; ++fm)
        #pragma unroll
        for (int fn = 0; fn < 4; ++fn)
            acc[fm][fn] = (f32x4){0.f, 0.f, 0.f, 0.f};

    for (int kt = 0; kt < CK / BK; ++kt) {
        uint4 va  = *reinterpret_cast<const uint4*>(aSrc);
        uint4 vb0 = *reinterpret_cast<const uint4*>(bSrc);
        uint4 vb1 = *reinterpret_cast<const uint4*>(bSrc + 8);
        *reinterpret_cast<uint4*>(sA + swA)  = va;
        *reinterpret_cast<uint4*>(sB + swB0) = vb0;
        *reinterpret_cast<uint4*>(sB + swB1) = vb1;
        aSrc += BK; bSrc += BK;
        __syncthreads();

        bf16x8 af[2], bfr[4];
        #pragma unroll
        for (int fm = 0; fm < 2; ++fm)
            af[fm] = *reinterpret_cast<const bf16x8*>(sA + raOff[fm]);
        #pragma unroll
        for (int fn = 0; fn < 4; ++fn)
            bfr[fn] = *reinterpret_cast<const bf16x8*>(sB + rbOff[fn]);

        #pragma unroll
        for (int fm = 0; fm < 2; ++fm)
            #pragma unroll
            for (int fn = 0; fn < 4; ++fn)
                acc[fm][fn] = __builtin_amdgcn_mfma_f32_16x16x32_bf16(
                    af[fm], bfr[fn], acc[fm][fn], 0, 0, 0);
        __syncthreads();
    }

    // epilogue: bias + eps-replace + store (rows < 196 only)
    const int r4 = (l >> 4) * 4;
    #pragma unroll
    for (int fm = 0; fm < 2; ++fm) {
        int mb = m0 + wm * 32 + fm * 16 + r4;
        #pragma unroll
        for (int fn = 0; fn < 4; ++fn) {
            int col = n0 + wn * 64 + fn * 16 + (l & 15);
            float bias = b_exp[e * CN + col];
            #pragma unroll
            for (int r = 0; r < 4; ++r) {
                int mrow = mb + r;
                if (mrow < NP) {
                    float v = acc[fm][fn][r] + bias;
                    if (v == 0.0f) v = 2.220446049250313e-16f;
                    out[((size_t)b * NP + mrow) * CN + col] = v;
                }
            }
        }
    }
}

extern "C" void kernel_launch(void* const* d_in, const int* in_sizes, int n_in,
                              void* d_out, int out_size, void* d_ws, size_t ws_size,
                              hipStream_t stream) {
    const float* x       = (const float*)d_in[0];
    const float* g       = (const float*)d_in[1];
    const float* noise   = (const float*)d_in[2];
    const float* w_gate  = (const float*)d_in[3];
    const float* w_noise = (const float*)d_in[4];
    const float* w_exp   = (const float*)d_in[5];
    const float* b_exp   = (const float*)d_in[6];
    float* out = (float*)d_out;

    char* ws = (char*)d_ws;
    int* eid      = (int*)ws;                                        // 256 B
    u16* patches  = (u16*)(ws + 1024);                               // 64*256*768*2 = 25165824 B
    u16* wbf      = (u16*)(ws + 1024 + (size_t)NB * MPAD * CK * 2);  // 8*768*768*2 = 9437184 B

    hipLaunchKernelGGL(gate_kernel, dim3(1), dim3(64), 0, stream,
                       g, noise, w_gate, w_noise, eid, out + (size_t)NB * NP * CN);
    hipLaunchKernelGGL(wconv_kernel, dim3((NE * CN * CK / 8) / 256), dim3(256), 0, stream,
                       w_exp, wbf);
    hipLaunchKernelGGL(patchify_kernel, dim3(NB * MPAD * 96 / 256), dim3(256), 0, stream,
                       x, patches);
    hipLaunchKernelGGL(gemm_kernel, dim3(CN / BN, MPAD / BM, NB), dim3(256), 0, stream,
                       patches, wbf, b_exp, eid, out);
}

// Round 2
// 74.804 us; speedup vs baseline: 1.5536x; 1.5536x over previous
//
#include <hip/hip_runtime.h>
#include <math.h>

typedef unsigned short u16;
typedef unsigned int   u32;

using bf16x8 = __attribute__((ext_vector_type(8))) short;
using f32x4  = __attribute__((ext_vector_type(4))) float;

#define NB   64      // batch
#define NE   8       // experts
#define DIN  320
#define NP   196     // real patches per image
#define MPAD 256     // padded rows per image
#define CK   768     // inner dim (C*P*P)
#define CN   768     // out features

#define BM 128
#define BN 128
#define BK 32        // LDS row = BK*2 = 64 bytes = 4 chunks of 16B

__device__ __forceinline__ u16 f2bf(float f) {
    u32 u = __builtin_bit_cast(u32, f);
    u += 0x7fffu + ((u >> 16) & 1u);
    return (u16)(u >> 16);
}

__device__ __forceinline__ void gload16(const void* g, void* l) {
    __builtin_amdgcn_global_load_lds(
        (const __attribute__((address_space(1))) void*)g,
        (__attribute__((address_space(3))) void*)l, 16, 0, 0);
}

// ---------------- gating + loss (parallel: thread = (b,e)) ----------------
__global__ __launch_bounds__(512) void gate_kernel(
    const float* __restrict__ g,
    const float* __restrict__ noise,
    const float* __restrict__ w_gate,
    const float* __restrict__ w_noise,
    int* __restrict__ eid,
    float* __restrict__ loss_out)
{
    __shared__ float sW[DIN][NE];
    __shared__ float sWn[DIN][NE];
    __shared__ float sNy[NB][NE];
    __shared__ float sProb[NB][NE];
    __shared__ int   sTop[NB];
    __shared__ float sImp[NE], sLoad[NE];

    int t = threadIdx.x;
    for (int i = t; i < DIN * NE; i += 512) {
        sW[i / NE][i % NE]  = w_gate[i];
        sWn[i / NE][i % NE] = w_noise[i];
    }
    __syncthreads();

    int b = t >> 3, e = t & 7;
    float cl = 0.f, nz = 0.f;
    const float* gr = g + b * DIN;
    #pragma unroll 4
    for (int i = 0; i < DIN; ++i) {
        float gv = gr[i];
        cl = fmaf(gv, sW[i][e], cl);
        nz = fmaf(gv, sWn[i][e], nz);
    }
    // jax.nn.softplus == max(x,0)+log1p(exp(-|x|))
    float sd = fmaxf(nz, 0.f) + log1pf(expf(-fabsf(nz))) + 0.01f;
    float ny = fmaf(noise[b * NE + e], sd, cl);
    sNy[b][e] = ny;
    __syncthreads();

    float v1 = -1e30f, v2 = -1e30f; int i1 = 0;
    #pragma unroll
    for (int k = 0; k < NE; ++k) {
        float v = sNy[b][k];
        if (v > v1) { v2 = v1; v1 = v; i1 = k; }
        else if (v > v2) { v2 = v; }
    }
    if (e == 0) { sTop[b] = i1; eid[b] = i1; }
    // is_in: noisy > 2nd-largest (thr_in=v2); else threshold is largest (v1)
    float thr = (ny > v2) ? v2 : v1;
    float z = (cl - thr) / sd;
    sProb[b][e] = 0.5f * (1.0f + erff(z * 0.7071067811865476f));
    __syncthreads();

    if (t < NE) {
        float imp = 0.f, ld = 0.f;
        for (int i = 0; i < NB; ++i) {
            imp += (sTop[i] == t) ? 1.0f : 0.0f;
            ld  += sProb[i][t];
        }
        sImp[t] = imp; sLoad[t] = ld;
    }
    __syncthreads();
    if (t == 0) {
        float mi = 0.f, ml = 0.f;
        for (int k = 0; k < NE; ++k) { mi += sImp[k]; ml += sLoad[k]; }
        mi *= (1.0f / NE); ml *= (1.0f / NE);
        float vi = 0.f, vl = 0.f;
        for (int k = 0; k < NE; ++k) {
            float d1 = sImp[k] - mi;  vi += d1 * d1;
            float d2 = sLoad[k] - ml; vl += d2 * d2;
        }
        vi *= (1.0f / (NE - 1)); vl *= (1.0f / (NE - 1));  // ddof=1
        loss_out[0] = (vi / (mi * mi + 1e-10f) + vl / (ml * ml + 1e-10f)) * 0.01f;
    }
}

// ---------------- w_exp fp32 -> bf16 ----------------
__global__ void wconv_kernel(const float* __restrict__ w, u16* __restrict__ wb)
{
    int idx = blockIdx.x * 256 + threadIdx.x;     // 8 elems per thread
    const float* src = w + (size_t)idx * 8;
    float4 f0 = *reinterpret_cast<const float4*>(src);
    float4 f1 = *reinterpret_cast<const float4*>(src + 4);
    uint4 o;
    o.x = (u32)f2bf(f0.x) | ((u32)f2bf(f0.y) << 16);
    o.y = (u32)f2bf(f0.z) | ((u32)f2bf(f0.w) << 16);
    o.z = (u32)f2bf(f1.x) | ((u32)f2bf(f1.y) << 16);
    o.w = (u32)f2bf(f1.z) | ((u32)f2bf(f1.w) << 16);
    *reinterpret_cast<uint4*>(wb + (size_t)idx * 8) = o;
}

// ---------------- patchify + bf16, pad rows [196,256) with zeros ----------------
__global__ void patchify_kernel(const float* __restrict__ x, u16* __restrict__ patches)
{
    int idx = blockIdx.x * 256 + threadIdx.x;
    int i8 = idx % 96;
    int p  = (idx / 96) % MPAD;
    int b  = idx / (96 * MPAD);
    u16* dst = patches + ((size_t)(b * MPAD + p)) * CK + i8 * 8;
    if (p >= NP) {
        uint4 z; z.x = 0; z.y = 0; z.z = 0; z.w = 0;
        *reinterpret_cast<uint4*>(dst) = z;
        return;
    }
    int gh = p / 14, gw = p % 14;
    int i0 = i8 * 8;
    int c   = i0 >> 8;
    int rem = i0 & 255;
    int ph  = rem >> 4;
    int pw0 = rem & 15;
    const float* src = x + (((size_t)(b * 3 + c) * 224 + gh * 16 + ph) * 224 + gw * 16 + pw0);
    float4 f0 = *reinterpret_cast<const float4*>(src);
    float4 f1 = *reinterpret_cast<const float4*>(src + 4);
    uint4 o;
    o.x = (u32)f2bf(f0.x) | ((u32)f2bf(f0.y) << 16);
    o.y = (u32)f2bf(f0.z) | ((u32)f2bf(f0.w) << 16);
    o.z = (u32)f2bf(f1.x) | ((u32)f2bf(f1.y) << 16);
    o.w = (u32)f2bf(f1.z) | ((u32)f2bf(f1.w) << 16);
    *reinterpret_cast<uint4*>(dst) = o;
}

// ---------------- expert-selected batched GEMM (m97 structure) ----------------
// grid: 768 linear blocks -> (image b, m-tile, n-tile); 256 thr = 4 waves (2x2),
// wave tile 64x64 (4x4 fragments of 16x16x32), global_load_lds staging with
// both-sides chunk swizzle c' = c ^ ((row>>2)&3).
__global__ __launch_bounds__(256, 3) void gemm_kernel(
    const u16* __restrict__ patches,
    const u16* __restrict__ wb,
    const float* __restrict__ b_exp,
    const int* __restrict__ eid,
    float* __restrict__ out)
{
    __shared__ char sA[BM * BK * 2];   // 8 KB
    __shared__ char sB[BN * BK * 2];   // 8 KB

    const int id = blockIdx.x;
    // bijective XCD swizzle: 96 consecutive virtual blocks (=8 images) per XCD
    const int v  = (id & 7) * 96 + (id >> 3);
    const int b  = v / 12;
    const int rr = v % 12;
    const int m0 = (rr / 6) * BM;
    const int n0 = (rr % 6) * BN;
    const int e  = eid[b];

    const int t  = threadIdx.x;
    const int l  = t & 63;
    const int w  = t >> 6;
    const int wm = w >> 1;
    const int wn = w & 1;

    // ---- staging addresses ----
    // wave w, part j in {0,1}: LDS bytes [w*2048 + j*1024 + l*16]
    // -> row r = w*32 + j*16 + (l>>2), chunk c' = l&3
    // global source chunk cg = c' ^ ((r>>2)&3) = (l&3) ^ (l>>4)
    const int rs  = (w << 5) + (l >> 2);          // row for j=0
    const u32 cg  = (u32)((l & 3) ^ (l >> 4));
    const u16* aSrc0 = patches + ((size_t)(b * MPAD) + m0 + rs) * CK + cg * 8;
    const u16* aSrc1 = aSrc0 + (size_t)16 * CK;
    const u16* bSrc0 = wb + (size_t)e * CK * CN + ((size_t)(n0 + rs)) * CK + cg * 8;
    const u16* bSrc1 = bSrc0 + (size_t)16 * CK;
    char* lA0 = sA + w * 2048;
    char* lA1 = lA0 + 1024;
    char* lB0 = sB + w * 2048;
    char* lB1 = lB0 + 1024;

    // ---- fragment read offsets (same swizzle) ----
    u32 aOff[4], bOff[4];
    #pragma unroll
    for (int fm = 0; fm < 4; ++fm) {
        int row = wm * 64 + fm * 16 + (l & 15);
        u32 c = (u32)(l >> 4) ^ (u32)((row >> 2) & 3);
        aOff[fm] = (u32)row * 64 + c * 16;
    }
    #pragma unroll
    for (int fn = 0; fn < 4; ++fn) {
        int row = wn * 64 + fn * 16 + (l & 15);
        u32 c = (u32)(l >> 4) ^ (u32)((row >> 2) & 3);
        bOff[fn] = (u32)row * 64 + c * 16;
    }

    f32x4 acc[4][4];
    #pragma unroll
    for (int fm = 0; fm < 4; ++fm)
        #pragma unroll
        for (int fn = 0; fn < 4; ++fn)
            acc[fm][fn] = (f32x4){0.f, 0.f, 0.f, 0.f};

    for (int kt = 0; kt < CK / BK; ++kt) {
        gload16(aSrc0, lA0);
        gload16(aSrc1, lA1);
        gload16(bSrc0, lB0);
        gload16(bSrc1, lB1);
        aSrc0 += BK; aSrc1 += BK; bSrc0 += BK; bSrc1 += BK;
        __syncthreads();   // drains vmcnt -> staged tile visible

        bf16x8 af[4], bfr[4];
        #pragma unroll
        for (int fm = 0; fm < 4; ++fm)
            af[fm] = *reinterpret_cast<const bf16x8*>(sA + aOff[fm]);
        #pragma unroll
        for (int fn = 0; fn < 4; ++fn)
            bfr[fn] = *reinterpret_cast<const bf16x8*>(sB + bOff[fn]);

        #pragma unroll
        for (int fm = 0; fm < 4; ++fm)
            #pragma unroll
            for (int fn = 0; fn < 4; ++fn)
                acc[fm][fn] = __builtin_amdgcn_mfma_f32_16x16x32_bf16(
                    af[fm], bfr[fn], acc[fm][fn], 0, 0, 0);
        __syncthreads();   // reads done before next stage overwrites
    }

    // ---- epilogue: bias + eps-replace + store rows < 196 ----
    const int r4 = (l >> 4) * 4;
    #pragma unroll
    for (int fm = 0; fm < 4; ++fm) {
        int mb = m0 + wm * 64 + fm * 16 + r4;
        #pragma unroll
        for (int fn = 0; fn < 4; ++fn) {
            int col = n0 + wn * 64 + fn * 16 + (l & 15);
            float bias = b_exp[e * CN + col];
            #pragma unroll
            for (int q = 0; q < 4; ++q) {
                int mrow = mb + q;
                if (mrow < NP) {
                    float vv = acc[fm][fn][q] + bias;
                    if (vv == 0.0f) vv = 2.220446049250313e-16f;
                    out[((size_t)b * NP + mrow) * CN + col] = vv;
                }
            }
        }
    }
}

extern "C" void kernel_launch(void* const* d_in, const int* in_sizes, int n_in,
                              void* d_out, int out_size, void* d_ws, size_t ws_size,
                              hipStream_t stream) {
    const float* x       = (const float*)d_in[0];
    const float* g       = (const float*)d_in[1];
    const float* noise   = (const float*)d_in[2];
    const float* w_gate  = (const float*)d_in[3];
    const float* w_noise = (const float*)d_in[4];
    const float* w_exp   = (const float*)d_in[5];
    const float* b_exp   = (const float*)d_in[6];
    float* out = (float*)d_out;

    char* ws = (char*)d_ws;
    int* eid      = (int*)ws;                                        // 256 B
    u16* patches  = (u16*)(ws + 1024);                               // 25165824 B
    u16* wbf      = (u16*)(ws + 1024 + (size_t)NB * MPAD * CK * 2);  // 9437184 B

    hipLaunchKernelGGL(gate_kernel, dim3(1), dim3(512), 0, stream,
                       g, noise, w_gate, w_noise, eid, out + (size_t)NB * NP * CN);
    hipLaunchKernelGGL(wconv_kernel, dim3((NE * CN * CK / 8) / 256), dim3(256), 0, stream,
                       w_exp, wbf);
    hipLaunchKernelGGL(patchify_kernel, dim3(NB * MPAD * 96 / 256), dim3(256), 0, stream,
                       x, patches);
    hipLaunchKernelGGL(gemm_kernel, dim3(CN / BN * MPAD / BM * NB), dim3(256), 0, stream,
                       patches, wbf, b_exp, eid, out);
}